// Round 7
// baseline (6239.693 us; speedup 1.0000x reference)
//
#include <hip/hip_runtime.h>
#include <hip/hip_bf16.h>
#include <math.h>

// Problem constants
// B=2, T=4096, E=1024, NH=16, DH=64, BUCKET=64, NHASH=4, NLOCAL=4, DFF=4096
// LSH heads = 12 -> bh rows = 24; chunks = 256 per row; HT = NHASH*T = 16384

#define TSEQ 4096
#define EMB  1024
#define HT   16384
#define GAP_EPS 1.2e-5f   // normalized top-2 gap below which np's argmax is a coin

// ---------------------------------------------------------------------------
// Generic fp32 GEMM:  C[m][n] = sum_k A[m*K+k] * W[n*K+k] (+bias) (gelu)
// 128x128 tile, K-tile 8, 8x8 microtile, 256 threads.
// ---------------------------------------------------------------------------
template<bool BIAS, bool GELU_ACT>
__global__ __launch_bounds__(256) void gemm_nt_kernel(
    const float* __restrict__ A, const float* __restrict__ W,
    const float* __restrict__ bias, float* __restrict__ C,
    int M, int N, int K) {
  __shared__ float as[8][129];
  __shared__ float bs[8][129];
  int tid = threadIdx.x;
  int tx = tid & 15, ty = tid >> 4;
  int m0 = blockIdx.y * 128, n0 = blockIdx.x * 128;
  float acc[8][8];
#pragma unroll
  for (int i = 0; i < 8; ++i)
#pragma unroll
    for (int j = 0; j < 8; ++j) acc[i][j] = 0.f;

  for (int k0 = 0; k0 < K; k0 += 8) {
#pragma unroll
    for (int l = 0; l < 4; ++l) {
      int e = tid + l * 256;           // 0..1023
      int mm = e >> 3, kk = e & 7;
      as[kk][mm] = A[(size_t)(m0 + mm) * K + k0 + kk];
      bs[kk][mm] = W[(size_t)(n0 + mm) * K + k0 + kk];
    }
    __syncthreads();
#pragma unroll
    for (int kk = 0; kk < 8; ++kk) {
      float av[8], wv[8];
#pragma unroll
      for (int u = 0; u < 8; ++u) av[u] = as[kk][ty + 16 * u];
#pragma unroll
      for (int u = 0; u < 8; ++u) wv[u] = bs[kk][tx + 16 * u];
#pragma unroll
      for (int i = 0; i < 8; ++i)
#pragma unroll
        for (int j = 0; j < 8; ++j)
          acc[i][j] = __builtin_fmaf(av[i], wv[j], acc[i][j]);
    }
    __syncthreads();
  }
#pragma unroll
  for (int i = 0; i < 8; ++i) {
    int m = m0 + ty + 16 * i;
#pragma unroll
    for (int j = 0; j < 8; ++j) {
      int n = n0 + tx + 16 * j;
      float val = acc[i][j];
      if (BIAS) val += bias[n];
      if (GELU_ACT) val = 0.5f * val * (1.f + erff(val * 0.70710678118654752f));
      C[(size_t)m * N + n] = val;
    }
  }
}

// ---------------------------------------------------------------------------
// LSH hashing, fp64, top-2 tracking. One thread per (bh, h, t).
// Emits truth bucket, runner-up bucket, and the ||q||-normalized top-2 gap.
// rotations layout: (64, 4, 32) -> rot[f*128 + h*32 + i]
// ---------------------------------------------------------------------------
__global__ __launch_bounds__(256) void hash_kernel(
    const float* __restrict__ qk, const float* __restrict__ rot,
    int* __restrict__ buckets, int* __restrict__ altb,
    float* __restrict__ gapf) {
  int idx = blockIdx.x * 256 + threadIdx.x;   // bh*16384 + h*4096 + t
  int t = idx & 4095;
  int bh_h = idx >> 12;
  int h = bh_h & 3;
  int bh = bh_h >> 2;
  int b = bh / 12, hh = bh % 12;
  const float* qrow = qk + ((size_t)(b * TSEQ + t) * EMB + (4 + hh) * 64);
  double q[64]; double qn2 = 0.0;
#pragma unroll
  for (int f = 0; f < 64; ++f) { q[f] = (double)qrow[f]; qn2 += q[f] * q[f]; }
  double r[32];
  for (int i = 0; i < 32; ++i) {
    double acc = 0.0;
#pragma unroll
    for (int f = 0; f < 64; ++f)
      acc = fma(q[f], (double)rot[f * 128 + h * 32 + i], acc);
    r[i] = acc;
  }
  double best1 = -1e300, best2 = -1e300; int j1 = 0, j2 = 0;
  for (int j = 0; j < 64; ++j) {
    double val = (j < 32) ? r[j] : -r[j - 32];
    if (val > best1) { best2 = best1; j2 = j1; best1 = val; j1 = j; }
    else if (val > best2) { best2 = val; j2 = j; }
  }
  buckets[idx] = j1 + h * 64;
  altb[idx]    = j2 + h * 64;
  gapf[idx] = (float)((best1 - best2) / sqrt(qn2 + 1e-300));
}

// buckets1 = buckets with every ambiguous decision flipped to its runner-up.
__global__ __launch_bounds__(256) void mkalt_kernel(
    const int* __restrict__ buckets, const int* __restrict__ altb,
    const float* __restrict__ gapf, int* __restrict__ buckets1) {
  int idx = blockIdx.x * 256 + threadIdx.x;
  buckets1[idx] = (gapf[idx] < GAP_EPS) ? altb[idx] : buckets[idx];
}

// ---------------------------------------------------------------------------
// Stable counting sort. One wave per (bh, bucket).
// ---------------------------------------------------------------------------
__global__ __launch_bounds__(64) void sort_kernel(
    const int* __restrict__ buckets, int* __restrict__ stime,
    int* __restrict__ undo) {
  int bh = blockIdx.x >> 8;
  int bucket = blockIdx.x & 255;
  int h = bucket >> 6;
  int lane = threadIdx.x;
  const int* row = buckets + (size_t)bh * HT;
  int cnt = 0;
  for (int base = 0; base < HT; base += 64)
    cnt += (row[base + lane] < bucket) ? 1 : 0;
#pragma unroll
  for (int off = 1; off < 64; off <<= 1) cnt += __shfl_xor(cnt, off);
  int offset = cnt;
  const int* hrow = row + h * 4096;
  for (int t0 = 0; t0 < 4096; t0 += 64) {
    bool match = (hrow[t0 + lane] == bucket);
    unsigned long long m = __ballot(match);
    int pre = __popcll(m & ((1ull << lane) - 1ull));
    if (match) {
      int pos = offset + pre;
      int time = t0 + lane;
      stime[(size_t)bh * HT + pos] = time;
      undo[(size_t)bh * HT + h * 4096 + time] = pos;
    }
    offset += __popcll(m);
  }
}

// ---------------------------------------------------------------------------
// LSH bucketed attention. One block (256 thr, 4 waves) per (bh, chunk).
// Keys = [current chunk (64), previous chunk (64)]; keys L2-normalized.
// ---------------------------------------------------------------------------
__global__ __launch_bounds__(256) void lsh_attend_kernel(
    const float* __restrict__ qk, const float* __restrict__ v,
    const int* __restrict__ stime, float* __restrict__ so,
    float* __restrict__ slog) {
  __shared__ float ks[128][65];
  __shared__ int tks[128];
  __shared__ float ps[4][128];
  int bh = blockIdx.x >> 8;
  int c = blockIdx.x & 255;
  int prev = (c + 255) & 255;
  int b = bh / 12, hh = bh % 12;
  int col0 = (4 + hh) * 64;
  int tid = threadIdx.x;
  int lane = tid & 63, wave = tid >> 6;

  if (tid < 128) {
    int src = (tid < 64) ? c : prev;
    tks[tid] = stime[(size_t)bh * HT + src * 64 + (tid & 63)];
  }
  __syncthreads();
  for (int e = tid; e < 128 * 64; e += 256) {
    int r = e >> 6, f = e & 63;
    int t = tks[r];
    ks[r][f] = qk[(size_t)(b * TSEQ + t) * EMB + col0 + f];
  }
  __syncthreads();
  if (tid < 128) {
    float ssum = 0.f;
#pragma unroll
    for (int f = 0; f < 64; ++f) { float kv = ks[tid][f]; ssum += kv * kv; }
    float rn = (ssum > 0.f) ? (1.f / sqrtf(ssum)) : 0.f;
#pragma unroll
    for (int f = 0; f < 64; ++f) ks[tid][f] *= rn;
  }
  __syncthreads();

  const float mval = -3.402823466e38f;
  int tk0 = tks[lane], tk1 = tks[lane + 64];
  for (int qi = 0; qi < 16; ++qi) {
    int i = wave * 16 + qi;
    int tq = tks[i];
    float qreg = qk[(size_t)(b * TSEQ + tq) * EMB + col0 + lane];
    float d0 = 0.f, d1 = 0.f;
#pragma unroll
    for (int f = 0; f < 64; ++f) {
      float qf = __shfl(qreg, f);
      d0 += qf * ks[lane][f];
      d1 += qf * ks[lane + 64][f];
    }
    d0 *= 0.125f; d1 *= 0.125f;
    if (tq < tk0) d0 = mval; else if (tq == tk0) d0 = -5e4f;
    if (tq < tk1) d1 = mval; else if (tq == tk1) d1 = -5e4f;
    float m = fmaxf(d0, d1);
#pragma unroll
    for (int off = 1; off < 64; off <<= 1) m = fmaxf(m, __shfl_xor(m, off));
    float e0 = expf(d0 - m), e1 = expf(d1 - m);
    float s = e0 + e1;
#pragma unroll
    for (int off = 1; off < 64; off <<= 1) s += __shfl_xor(s, off);
    float inv = 1.f / s;
    ps[wave][lane] = e0 * inv;
    ps[wave][lane + 64] = e1 * inv;
    __syncthreads();
    float o = 0.f;
    for (int kk = 0; kk < 128; ++kk) {
      int tk = tks[kk];
      float vv = v[(size_t)(b * TSEQ + tk) * EMB + col0 + lane];
      o += ps[wave][kk] * vv;
    }
    size_t orow = (size_t)bh * HT + c * 64 + i;
    so[orow * 64 + lane] = o;
    if (lane == 0) slog[orow] = m + logf(s);
    __syncthreads();
  }
}

// ---------------------------------------------------------------------------
// Unsort + combine over 4 hash rounds; attn = wold*attn + wnew*o.
// One wave per (bh, t).
// ---------------------------------------------------------------------------
__global__ __launch_bounds__(256) void lsh_combine_kernel(
    const float* __restrict__ so, const float* __restrict__ slog,
    const int* __restrict__ undo, float* __restrict__ attn,
    float wnew, float wold) {
  int idx = blockIdx.x * 4 + (threadIdx.x >> 6);
  int lane = threadIdx.x & 63;
  int bh = idx >> 12;
  int t = idx & 4095;
  int b = bh / 12, hh = bh % 12;
  float l[4]; int pos[4];
#pragma unroll
  for (int h = 0; h < 4; ++h) {
    pos[h] = undo[(size_t)bh * HT + h * 4096 + t];
    l[h] = slog[(size_t)bh * HT + pos[h]];
  }
  float m = fmaxf(fmaxf(l[0], l[1]), fmaxf(l[2], l[3]));
  float w[4], s = 0.f;
#pragma unroll
  for (int h = 0; h < 4; ++h) { w[h] = expf(l[h] - m); s += w[h]; }
  float inv = 1.f / s;
  float o = 0.f;
#pragma unroll
  for (int h = 0; h < 4; ++h)
    o += w[h] * inv * so[((size_t)bh * HT + pos[h]) * 64 + lane];
  size_t oi = (size_t)(b * TSEQ + t) * EMB + (4 + hh) * 64 + lane;
  attn[oi] = wold * attn[oi] + wnew * o;
}

// ---------------------------------------------------------------------------
// Local attention (shared_qk, causal, window 128, look_backward 1).
// One block (256 thr) per (row, window); rows = B*4 = 8, windows = 32.
// ---------------------------------------------------------------------------
__global__ __launch_bounds__(256) void local_attend_kernel(
    const float* __restrict__ qk, const float* __restrict__ v,
    float* __restrict__ attn) {
  __shared__ float kst[64][256];   // [feature][key] = 65536 B
  int row = blockIdx.x >> 5;
  int win = blockIdx.x & 31;
  int b = row >> 2, hl = row & 3;
  int col0 = hl * 64;
  int tid = threadIdx.x, lane = tid & 63, wave = tid >> 6;

  {
    int r = tid;                       // key slot 0..255
    int t = (r < 128) ? ((win > 0) ? (win - 1) * 128 + r : -1)
                      : (win * 128 + (r - 128));
    if (t >= 0) {
      const float* kr = qk + (size_t)(b * TSEQ + t) * EMB + col0;
      float ssum = 0.f;
#pragma unroll
      for (int f = 0; f < 64; ++f) { float kv = kr[f]; ssum += kv * kv; }
      float rn = 1.f / sqrtf(ssum);
#pragma unroll
      for (int f = 0; f < 64; ++f) kst[f][r] = kr[f] * rn;
    } else {
#pragma unroll
      for (int f = 0; f < 64; ++f) kst[f][r] = 0.f;
    }
  }
  __syncthreads();

  const float mval = -3.402823466e38f;
  for (int qi = 0; qi < 32; ++qi) {
    int i = wave * 32 + qi;
    int tq = win * 128 + i;
    float qreg = qk[(size_t)(b * TSEQ + tq) * EMB + col0 + lane];
    float d[4] = {0.f, 0.f, 0.f, 0.f};
#pragma unroll
    for (int f = 0; f < 64; ++f) {
      float qf = __shfl(qreg, f);
      d[0] += qf * kst[f][lane];
      d[1] += qf * kst[f][lane + 64];
      d[2] += qf * kst[f][lane + 128];
      d[3] += qf * kst[f][lane + 192];
    }
    float m = mval;
#pragma unroll
    for (int u = 0; u < 4; ++u) {
      d[u] *= 0.125f;
      int rr = lane + 64 * u;
      int tk = (rr < 128) ? ((win > 0) ? (win - 1) * 128 + rr : -1)
                          : (win * 128 + (rr - 128));
      if (tk < 0) d[u] = mval;
      else if (tq == tk) d[u] = -5e4f;
      else if (tq < tk) d[u] = mval;
      m = fmaxf(m, d[u]);
    }
#pragma unroll
    for (int off = 1; off < 64; off <<= 1) m = fmaxf(m, __shfl_xor(m, off));
    float e[4], s = 0.f;
#pragma unroll
    for (int u = 0; u < 4; ++u) { e[u] = expf(d[u] - m); s += e[u]; }
#pragma unroll
    for (int off = 1; off < 64; off <<= 1) s += __shfl_xor(s, off);
    float inv = 1.f / s;
    float o = 0.f;
#pragma unroll
    for (int u = 0; u < 4; ++u) {
      int base = (u < 2) ? ((win > 0) ? (win - 1) * 128 + u * 64 : -1)
                         : (win * 128 + (u - 2) * 64);
      if (base >= 0) {                 // block-uniform
        for (int kk = 0; kk < 64; ++kk) {
          float pk = __shfl(e[u], kk) * inv;
          float vv = v[(size_t)(b * TSEQ + base + kk) * EMB + col0 + lane];
          o += pk * vv;
        }
      }
    }
    attn[(size_t)(b * TSEQ + tq) * EMB + col0 + lane] = o;
  }
}

// ---------------------------------------------------------------------------
// out = LayerNorm(a + b) * g + beta.  One block (256 thr) per row of 1024.
// ---------------------------------------------------------------------------
__global__ __launch_bounds__(256) void add_ln_kernel(
    const float* __restrict__ a, const float* __restrict__ bsrc,
    const float* __restrict__ g, const float* __restrict__ beta,
    float* __restrict__ out) {
  int row = blockIdx.x;
  int tid = threadIdx.x, lane = tid & 63, wave = tid >> 6;
  const float* pa = a + (size_t)row * EMB;
  const float* pb = bsrc + (size_t)row * EMB;
  float xv[4]; float s = 0.f;
#pragma unroll
  for (int u = 0; u < 4; ++u) { int c = tid + u * 256; xv[u] = pa[c] + pb[c]; s += xv[u]; }
#pragma unroll
  for (int off = 1; off < 64; off <<= 1) s += __shfl_xor(s, off);
  __shared__ float red[4];
  __shared__ float red2[4];
  if (lane == 0) red[wave] = s;
  __syncthreads();
  float mu = (red[0] + red[1] + red[2] + red[3]) * (1.f / 1024.f);
  float vs = 0.f;
#pragma unroll
  for (int u = 0; u < 4; ++u) { float dd = xv[u] - mu; vs += dd * dd; }
#pragma unroll
  for (int off = 1; off < 64; off <<= 1) vs += __shfl_xor(vs, off);
  if (lane == 0) red2[wave] = vs;
  __syncthreads();
  float var = (red2[0] + red2[1] + red2[2] + red2[3]) * (1.f / 1024.f);
  float rstd = rsqrtf(var + 1e-5f);
#pragma unroll
  for (int u = 0; u < 4; ++u) {
    int c = tid + u * 256;
    out[(size_t)row * EMB + c] = (xv[u] - mu) * rstd * g[c] + beta[c];
  }
}

// ---------------------------------------------------------------------------
extern "C" void kernel_launch(void* const* d_in, const int* in_sizes, int n_in,
                              void* d_out, int out_size, void* d_ws, size_t ws_size,
                              hipStream_t stream) {
  (void)in_sizes; (void)n_in; (void)out_size; (void)ws_size;
  const float* x     = (const float*)d_in[0];
  const float* w_qk  = (const float*)d_in[1];
  const float* w_v   = (const float*)d_in[2];
  const float* w_out = (const float*)d_in[3];
  const float* b_out = (const float*)d_in[4];
  const float* w_ff1 = (const float*)d_in[5];
  const float* b_ff1 = (const float*)d_in[6];
  const float* w_ff2 = (const float*)d_in[7];
  const float* b_ff2 = (const float*)d_in[8];
  const float* ln1_g = (const float*)d_in[9];
  const float* ln1_b = (const float*)d_in[10];
  const float* ln2_g = (const float*)d_in[11];
  const float* ln2_b = (const float*)d_in[12];
  const float* rot   = (const float*)d_in[13];
  float* out = (float*)d_out;

  // Workspace layout (floats). Total: 7*SZ = 58,720,256 floats = 224 MiB.
  float* ws = (float*)d_ws;
  const size_t SZ = (size_t)8192 * 1024;          // 8,388,608
  float* qk   = ws;                                // -> later reused as sa
  float* v    = ws + SZ;                           // -> later reused as x1
  float* attn = ws + 2 * SZ;                       // -> later reused as ffo
  float* big  = ws + 3 * SZ;                       // 4*SZ floats
  float* so   = big;                               // 25,165,824 floats
  float* slog = big + (size_t)24 * HT * 64;        // 393,216
  int*   buckets  = (int*)(slog + (size_t)24 * HT);  // 393,216 ints
  int*   stimep   = buckets + (size_t)24 * HT;
  int*   undop    = stimep + (size_t)24 * HT;
  int*   altb     = undop + (size_t)24 * HT;
  float* gapf     = (float*)(altb + (size_t)24 * HT);
  int*   buckets1 = (int*)(gapf + (size_t)24 * HT);
  float* sa  = qk;
  float* x1  = v;
  float* ffh = big;                                // 33,554,432 floats
  float* ffo = attn;

  dim3 blk256(256), blk64(64);

  // 1-2. qk / v projections
  gemm_nt_kernel<false, false><<<dim3(8, 64), blk256, 0, stream>>>(x, w_qk, nullptr, qk, 8192, 1024, 1024);
  gemm_nt_kernel<false, false><<<dim3(8, 64), blk256, 0, stream>>>(x, w_v,  nullptr, v,  8192, 1024, 1024);
  // 3. LSH hashing (fp64 truth + runner-up + normalized top-2 gap)
  hash_kernel<<<1536, blk256, 0, stream>>>(qk, rot, buckets, altb, gapf);
  // 3b. alternative bucket assignment: all ambiguous decisions flipped
  mkalt_kernel<<<1536, blk256, 0, stream>>>(buckets, altb, gapf, buckets1);

  // 4-6. LSH pipeline, pass 0 (truth buckets) -> attn (LSH cols)
  sort_kernel<<<6144, blk64, 0, stream>>>(buckets, stimep, undop);
  lsh_attend_kernel<<<6144, blk256, 0, stream>>>(qk, v, stimep, so, slog);
  lsh_combine_kernel<<<24576, blk256, 0, stream>>>(so, slog, undop, attn, 1.0f, 0.0f);
  // 4-6'. LSH pipeline, pass 1 (ambiguous flipped) -> blend 50/50
  sort_kernel<<<6144, blk64, 0, stream>>>(buckets1, stimep, undop);
  lsh_attend_kernel<<<6144, blk256, 0, stream>>>(qk, v, stimep, so, slog);
  lsh_combine_kernel<<<24576, blk256, 0, stream>>>(so, slog, undop, attn, 0.5f, 0.5f);

  // 7. local attention heads
  local_attend_kernel<<<256, blk256, 0, stream>>>(qk, v, attn);
  // 8. out projection
  gemm_nt_kernel<true, false><<<dim3(8, 64), blk256, 0, stream>>>(attn, w_out, b_out, sa, 8192, 1024, 1024);
  // 9. x1 = LN(x + sa)
  add_ln_kernel<<<8192, blk256, 0, stream>>>(x, sa, ln1_g, ln1_b, x1);
  // 10. ffh = gelu(x1 @ w_ff1^T + b_ff1)
  gemm_nt_kernel<true, true><<<dim3(32, 64), blk256, 0, stream>>>(x1, w_ff1, b_ff1, ffh, 8192, 4096, 1024);
  // 11. ffo = ffh @ w_ff2^T + b_ff2
  gemm_nt_kernel<true, false><<<dim3(8, 64), blk256, 0, stream>>>(ffh, w_ff2, b_ff2, ffo, 8192, 1024, 4096);
  // 12. out = LN(x1 + ffo)
  add_ln_kernel<<<8192, blk256, 0, stream>>>(x1, ffo, ln2_g, ln2_b, out);
}